// Round 3
// baseline (571.433 us; speedup 1.0000x reference)
//
#include <hip/hip_runtime.h>
#include <hip/hip_bf16.h>

#define N 2048
#define DT 256
#define ET 32
#define EC 128
#define NC 5
#define FS 80   // feats row stride (padded, 16B-aligned rows)
#define FD 69   // used feature cols (32 te + 32 fe + 5 onehot)

typedef __hip_bfloat16 bf16;

// A_t, A_f <- identity (Ah = A + I; scatter fills off-diagonal only)
__global__ void k_init_identity(float* __restrict__ At, float* __restrict__ Af){
    int idx4 = blockIdx.x*blockDim.x + threadIdx.x; // over N*N/4
    int base = idx4 << 2;
    int row = base >> 11;       // /N
    int col = base & (N-1);
    float4 v;
    v.x = (col+0==row)?1.f:0.f;
    v.y = (col+1==row)?1.f:0.f;
    v.z = (col+2==row)?1.f:0.f;
    v.w = (col+3==row)?1.f:0.f;
    ((float4*)At)[idx4] = v;
    ((float4*)Af)[idx4] = v;
}

// A[dst*N + src] = w  (edge_index[0]=src, edge_index[1]=dst; src!=dst)
__global__ void k_scatter(const int* __restrict__ ei, const float* __restrict__ tw,
                          const float* __restrict__ fw, float* __restrict__ At,
                          float* __restrict__ Af, int E){
    int k = blockIdx.x*blockDim.x + threadIdx.x;
    if (k >= E) return;
    int s = ei[k];
    int d = ei[E+k];
    size_t off = (size_t)d*N + s;
    At[off] = tw[k];
    Af[off] = fw[k];
}

// dis[row] = deg>0 ? 1/sqrt(sum_j A[row][j]) : 0
__global__ void k_row_rsqrt(const float* __restrict__ A, float* __restrict__ dis){
    int row = blockIdx.x;
    const float4* Ar = (const float4*)(A + (size_t)row*N);
    float s = 0.f;
    for (int i = threadIdx.x; i < N/4; i += 256){
        float4 v = Ar[i];
        s += (v.x+v.y)+(v.z+v.w);
    }
    #pragma unroll
    for (int off = 32; off > 0; off >>= 1) s += __shfl_xor(s, off, 64);
    __shared__ float red[4];
    int wid = threadIdx.x >> 6;
    if ((threadIdx.x & 63) == 0) red[wid] = s;
    __syncthreads();
    if (threadIdx.x == 0){
        float deg = red[0]+red[1]+red[2]+red[3];
        dis[row] = (deg > 0.f) ? 1.0f/sqrtf(deg) : 0.f;
    }
}

// Z[j][f] = dis[j] * (X[j,:] @ W[:,f])   X:[N,DT] fp32, W:[DT,ET] fp32
__global__ void k_xw_scale(const float* __restrict__ X, const float* __restrict__ W,
                           const float* __restrict__ dis, float* __restrict__ Z){
    __shared__ float Ws[DT*ET]; // 32 KB
    __shared__ float Xs[8*DT];  // 8 KB
    int t = threadIdx.x;
    for (int idx = t; idx < DT*ET; idx += 256) Ws[idx] = W[idx];
    int i0 = blockIdx.x*8;
    for (int idx = t; idx < 8*DT; idx += 256) Xs[idx] = X[(size_t)i0*DT + idx];
    __syncthreads();
    int r = t >> 5, f = t & 31;
    const float* xr = Xs + r*DT;
    float acc = 0.f;
    #pragma unroll 8
    for (int d = 0; d < DT; ++d) acc += xr[d]*Ws[d*ET+f];
    int i = i0 + r;
    Z[(size_t)i*ET+f] = dis[i]*acc;
}

// out[i][f0..f0+3] = lrelu(dis[i] * sum_j A[i][j]*Z[j][f] + bias[f]) ; 8 rows/block
template<int F>
__global__ void k_agg(const float* __restrict__ A, const float* __restrict__ Z,
                      const float* __restrict__ dis, const float* __restrict__ bias,
                      float* __restrict__ outp, int outStride, int colOff){
    const int LF = F/4;
    int t = threadIdx.x;
    int tr = t / LF;
    int tf = t % LF;
    int i = blockIdx.x*8 + tr;
    int f0 = tf*4;
    const float4* Ar = (const float4*)(A + (size_t)i*N);
    float ax=0.f, ay=0.f, az=0.f, aw=0.f;
    for (int j4 = 0; j4 < N/4; ++j4){
        float4 a = Ar[j4];
        const float* zb = Z + (size_t)(j4*4)*F + f0;
        float4 z0 = *(const float4*)(zb);
        float4 z1 = *(const float4*)(zb + F);
        float4 z2 = *(const float4*)(zb + 2*F);
        float4 z3 = *(const float4*)(zb + 3*F);
        ax += a.x*z0.x + a.y*z1.x + a.z*z2.x + a.w*z3.x;
        ay += a.x*z0.y + a.y*z1.y + a.z*z2.y + a.w*z3.y;
        az += a.x*z0.z + a.y*z1.z + a.z*z2.z + a.w*z3.z;
        aw += a.x*z0.w + a.y*z1.w + a.z*z2.w + a.w*z3.w;
    }
    float dv = dis[i];
    float4 o;
    float v0 = dv*ax + bias[f0+0]; o.x = v0 > 0.f ? v0 : 0.01f*v0;
    float v1 = dv*ay + bias[f0+1]; o.y = v1 > 0.f ? v1 : 0.01f*v1;
    float v2 = dv*az + bias[f0+2]; o.z = v2 > 0.f ? v2 : 0.01f*v2;
    float v3 = dv*aw + bias[f0+3]; o.w = v3 > 0.f ? v3 : 0.01f*v3;
    *(float4*)(outp + (size_t)i*outStride + colOff + f0) = o;
}

// one-hot cols 64..68: support rows (i < n - query) get cols[c]=1 if class c in labels
__global__ void k_onehot(const int* __restrict__ labels, const int* __restrict__ qsize,
                         float* __restrict__ feats){
    __shared__ float cols[NC];
    int t = threadIdx.x;
    if (t < NC) cols[t] = 0.f;
    __syncthreads();
    for (int idx = t; idx < N; idx += 256){
        int l = labels[idx];
        if (l >= 0 && l < NC) cols[l] = 1.f;   // benign race: all write 1.0
    }
    __syncthreads();
    int nsupport = N - qsize[0];
    int i = blockIdx.x*256 + t;
    float m = (i < nsupport) ? 1.f : 0.f;
    #pragma unroll
    for (int c = 0; c < NC; ++c) feats[(size_t)i*FS + 2*ET + c] = m*cols[c];
}

// Aw[i][j] = (i==j) ? 1 : 1/(L1(fd_i,fd_j)+1e-5)  (diag 1 == Aw + I already)
__global__ void k_build_aw(const float* __restrict__ feats, float* __restrict__ Aw){
    __shared__ float fi[64*65];
    __shared__ float fj[64*65];
    int t = threadIdx.x;
    int i0 = blockIdx.x*64, j0 = blockIdx.y*64;
    {
        int row = t >> 2;          // 0..63
        int seg = (t & 3) * 16;    // float offset
        const float4* si = (const float4*)(feats + (size_t)(i0+row)*FS + seg);
        const float4* sj = (const float4*)(feats + (size_t)(j0+row)*FS + seg);
        #pragma unroll
        for (int s = 0; s < 4; ++s){
            float4 v = si[s];
            float4 w = sj[s];
            int c = seg + s*4;
            fi[row*65+c+0]=v.x; fi[row*65+c+1]=v.y; fi[row*65+c+2]=v.z; fi[row*65+c+3]=v.w;
            fj[row*65+c+0]=w.x; fj[row*65+c+1]=w.y; fj[row*65+c+2]=w.z; fj[row*65+c+3]=w.w;
        }
    }
    __syncthreads();
    int tx = t & 15, ty = t >> 4;
    float acc[4][4];
    #pragma unroll
    for (int u=0;u<4;++u)
        #pragma unroll
        for (int v=0;v<4;++v) acc[u][v]=0.f;
    for (int k = 0; k < 64; ++k){
        float a0 = fi[(ty*4+0)*65+k], a1 = fi[(ty*4+1)*65+k];
        float a2 = fi[(ty*4+2)*65+k], a3 = fi[(ty*4+3)*65+k];
        float b0 = fj[(tx*4+0)*65+k], b1 = fj[(tx*4+1)*65+k];
        float b2 = fj[(tx*4+2)*65+k], b3 = fj[(tx*4+3)*65+k];
        acc[0][0]+=fabsf(a0-b0); acc[0][1]+=fabsf(a0-b1); acc[0][2]+=fabsf(a0-b2); acc[0][3]+=fabsf(a0-b3);
        acc[1][0]+=fabsf(a1-b0); acc[1][1]+=fabsf(a1-b1); acc[1][2]+=fabsf(a1-b2); acc[1][3]+=fabsf(a1-b3);
        acc[2][0]+=fabsf(a2-b0); acc[2][1]+=fabsf(a2-b1); acc[2][2]+=fabsf(a2-b2); acc[2][3]+=fabsf(a2-b3);
        acc[3][0]+=fabsf(a3-b0); acc[3][1]+=fabsf(a3-b1); acc[3][2]+=fabsf(a3-b2); acc[3][3]+=fabsf(a3-b3);
    }
    #pragma unroll
    for (int u = 0; u < 4; ++u){
        int gi = i0 + ty*4 + u;
        float4 o;
        float* po = (float*)&o;
        #pragma unroll
        for (int v = 0; v < 4; ++v){
            int gj = j0 + tx*4 + v;
            po[v] = (gi==gj) ? 1.0f : 1.0f/(acc[u][v] + 1e-5f);
        }
        *(float4*)(Aw + (size_t)gi*N + j0 + tx*4) = o;
    }
}

// Zc[i][f] = dis_w[i] * (feats[i,0:69] @ Wc[:,f])
__global__ void k_featswc(const float* __restrict__ feats, const float* __restrict__ Wc,
                          const float* __restrict__ dis_w, float* __restrict__ Zc){
    __shared__ float Wcs[FD*EC]; // 34.5 KB
    int t = threadIdx.x; // 128
    for (int idx = t; idx < FD*EC; idx += 128) Wcs[idx] = Wc[idx];
    __syncthreads();
    int i0 = blockIdx.x*16;
    for (int r = 0; r < 16; ++r){
        int i = i0 + r;
        const float* fr = feats + (size_t)i*FS;
        float acc = 0.f;
        #pragma unroll
        for (int d = 0; d < FD; ++d) acc += fr[d]*Wcs[d*EC+t];
        Zc[(size_t)i*EC+t] = dis_w[i]*acc;
    }
}

// out[i][c] = emb[i,:] @ Wo[:,c] + bo[c]   (fp32 output!)
__global__ void k_final(const float* __restrict__ emb, const float* __restrict__ Wo,
                        const float* __restrict__ bo, float* __restrict__ out){
    __shared__ float Wos[EC*NC];
    __shared__ float bos[NC];
    int t = threadIdx.x;
    for (int idx = t; idx < EC*NC; idx += 256) Wos[idx] = Wo[idx];
    if (t < NC) bos[t] = bo[t];
    __syncthreads();
    int idx = blockIdx.x*256 + t;   // grid exact: N*NC/256
    int i = idx / NC;
    int c = idx - i*NC;
    float acc = bos[c];
    const float* er = emb + (size_t)i*EC;
    #pragma unroll 8
    for (int f = 0; f < EC; ++f) acc += er[f]*Wos[f*NC+c];
    out[idx] = acc;
}

extern "C" void kernel_launch(void* const* d_in, const int* in_sizes, int n_in,
                              void* d_out, int out_size, void* d_ws, size_t ws_size,
                              hipStream_t stream) {
    const float* time_features = (const float*)d_in[0];
    const int*   edge_index    = (const int*)d_in[1];
    const float* tw            = (const float*)d_in[2];
    const float* freq_features = (const float*)d_in[3];
    const float* fw            = (const float*)d_in[4];
    const int*   labels        = (const int*)d_in[5];
    const int*   qsize         = (const int*)d_in[7];
    const float* Wt  = (const float*)d_in[8];
    const float* bt  = (const float*)d_in[9];
    const float* Wf  = (const float*)d_in[10];
    const float* bfv = (const float*)d_in[11];
    const float* Wc  = (const float*)d_in[12];
    const float* bc  = (const float*)d_in[13];
    const float* Wo  = (const float*)d_in[14];
    const float* bo  = (const float*)d_in[15];
    float* out = (float*)d_out;
    int E = in_sizes[2];

    float* ws    = (float*)d_ws;
    float* At    = ws;                        // N*N
    float* Af    = At + (size_t)N*N;          // N*N
    float* Zt    = Af + (size_t)N*N;          // N*ET
    float* Zf    = Zt + (size_t)N*ET;         // N*ET
    float* dis_t = Zf + (size_t)N*ET;         // N
    float* dis_f = dis_t + N;                 // N
    float* dis_w = dis_f + N;                 // N
    float* feats = dis_w + N;                 // N*FS
    float* Zc    = feats + (size_t)N*FS;      // N*EC
    float* emb   = Zc + (size_t)N*EC;         // N*EC
    float* Aw    = At;                        // reuse A_t space after te/fe done

    k_init_identity<<<(N*N/4)/256, 256, 0, stream>>>(At, Af);
    k_scatter<<<(E+255)/256, 256, 0, stream>>>(edge_index, tw, fw, At, Af, E);
    k_row_rsqrt<<<N, 256, 0, stream>>>(At, dis_t);
    k_row_rsqrt<<<N, 256, 0, stream>>>(Af, dis_f);
    k_xw_scale<<<N/8, 256, 0, stream>>>(time_features, Wt, dis_t, Zt);
    k_xw_scale<<<N/8, 256, 0, stream>>>(freq_features, Wf, dis_f, Zf);
    k_agg<ET><<<N/8, 64, 0, stream>>>(At, Zt, dis_t, bt,  feats, FS, 0);
    k_agg<ET><<<N/8, 64, 0, stream>>>(Af, Zf, dis_f, bfv, feats, FS, ET);
    k_onehot<<<N/256, 256, 0, stream>>>(labels, qsize, feats);
    dim3 g2(N/64, N/64);
    k_build_aw<<<g2, 256, 0, stream>>>(feats, Aw);
    k_row_rsqrt<<<N, 256, 0, stream>>>(Aw, dis_w);
    k_featswc<<<N/16, 128, 0, stream>>>(feats, Wc, dis_w, Zc);
    k_agg<EC><<<N/8, 256, 0, stream>>>(Aw, Zc, dis_w, bc, emb, EC, 0);
    k_final<<<(N*NC)/256, 256, 0, stream>>>(emb, Wo, bo, out);
}

// Round 4
// 305.855 us; speedup vs baseline: 1.8683x; 1.8683x over previous
//
#include <hip/hip_runtime.h>
#include <hip/hip_bf16.h>

#define N 2048
#define NM1 2047
#define DT 256
#define ET 32
#define EC 128
#define NC 5
#define FS 80    // feats row stride (floats)
#define FD 69    // used feature cols
#define KC_ET 16 // k-chunks for ET GEMMs (chunk = 128)
#define KC_EC 8  // k-chunks for EC GEMM (chunk = 256)

typedef __hip_bfloat16 bf16;

// ---- deg[d] = sum_s!=d A[d,s], A[d,s] = tw[s*2047 + d - (d>s)] ----
// read tw/fw coalesced (rows s contiguous), bucket into LDS by d, flush once.
__global__ __launch_bounds__(256) void k_deg(const float* __restrict__ tw,
                                             const float* __restrict__ fw,
                                             float* __restrict__ degT,
                                             float* __restrict__ degF){
    __shared__ float ldT[N];
    __shared__ float ldF[N];
    int t = threadIdx.x;
    for (int d = t; d < N; d += 256){ ldT[d] = 0.f; ldF[d] = 0.f; }
    __syncthreads();
    int s0 = blockIdx.x * 16;
    for (int r = 0; r < 16; ++r){
        int s = s0 + r;
        const float* twr = tw + (size_t)s * NM1;
        const float* fwr = fw + (size_t)s * NM1;
        for (int p = t; p < NM1; p += 256){
            int d = p + (p >= s ? 1 : 0);
            atomicAdd(&ldT[d], twr[p]);
            atomicAdd(&ldF[d], fwr[p]);
        }
    }
    __syncthreads();
    for (int d = t; d < N; d += 256){
        atomicAdd(&degT[d], ldT[d]);
        atomicAdd(&degF[d], ldF[d]);
    }
}

// ---- cols[c] = 1 if class c appears in labels ----
__global__ void k_labelmask(const int* __restrict__ labels, float* __restrict__ cols){
    __shared__ float lc[NC];
    int t = threadIdx.x;
    if (t < NC) lc[t] = 0.f;
    __syncthreads();
    for (int i = t; i < N; i += 256){
        int l = labels[i];
        if (l >= 0 && l < NC) lc[l] = 1.f;  // benign race, all write 1.0
    }
    __syncthreads();
    if (t < NC) cols[t] = lc[t];
}

// ---- Z[j][f] = rsqrt(1+deg[j]) * (X[j,:] @ W[:,f]) ----
__global__ __launch_bounds__(256) void k_xw_scale(const float* __restrict__ X,
                                                  const float* __restrict__ W,
                                                  const float* __restrict__ deg,
                                                  float* __restrict__ Z){
    __shared__ float Ws[DT*ET]; // 32 KB
    __shared__ float Xs[8*DT];  // 8 KB
    int t = threadIdx.x;
    for (int idx = t; idx < DT*ET; idx += 256) Ws[idx] = W[idx];
    int i0 = blockIdx.x*8;
    for (int idx = t; idx < 8*DT; idx += 256) Xs[idx] = X[(size_t)i0*DT + idx];
    __syncthreads();
    int r = t >> 5, f = t & 31;
    const float* xr = Xs + r*DT;
    float acc = 0.f;
    #pragma unroll 8
    for (int d = 0; d < DT; ++d) acc += xr[d]*Ws[d*ET+f];
    int i = i0 + r;
    Z[(size_t)i*ET+f] = rsqrtf(1.f + deg[i])*acc;
}

// ---- split-K GEMM: P[kc][i][f] = sum_{k in chunk, k!=i} A[i,k]*Z[k][f], both graphs ----
// A[i,k] = tw[k*2047 + i - (i>k)] (coalesced over i for fixed k)
__global__ __launch_bounds__(256) void k_agg_et(const float* __restrict__ tw,
                                                const float* __restrict__ fw,
                                                const float* __restrict__ Zt,
                                                const float* __restrict__ Zf,
                                                float* __restrict__ Pt,
                                                float* __restrict__ Pf){
    __shared__ float Ast[64*68];
    __shared__ float Asf[64*68];
    __shared__ float Zst[64*ET];
    __shared__ float Zsf[64*ET];
    int t = threadIdx.x;
    int i0 = blockIdx.x*64;
    int kc = blockIdx.y;          // 0..15
    int k0 = kc*128;
    int lane_i = t & 63;
    int krow0  = (t >> 6)*16;     // 16 k-rows per thread
    int gi = i0 + lane_i;
    int tf = t & 31;
    int tr = t >> 5;              // 0..7  -> rows tr*8+u
    float accT[8], accF[8];
    #pragma unroll
    for (int u = 0; u < 8; ++u){ accT[u]=0.f; accF[u]=0.f; }

    for (int kt = 0; kt < 2; ++kt){
        int kb = k0 + kt*64;
        #pragma unroll 4
        for (int e = 0; e < 16; ++e){
            int kl = krow0 + e;
            int k  = kb + kl;
            float vt, vf;
            if (gi == k){ vt = 0.f; vf = 0.f; }
            else {
                size_t base = (size_t)k*NM1 + gi - (gi > k ? 1 : 0);
                vt = tw[base]; vf = fw[base];
            }
            Ast[kl*68 + lane_i] = vt;
            Asf[kl*68 + lane_i] = vf;
        }
        #pragma unroll
        for (int h = 0; h < 2; ++h){
            int id = t + h*256;       // 0..511 float4 ids
            int row = id >> 3;
            int c4  = (id & 7)*4;
            *(float4*)&Zst[row*ET + c4] = *(const float4*)&Zt[(size_t)(kb+row)*ET + c4];
            *(float4*)&Zsf[row*ET + c4] = *(const float4*)&Zf[(size_t)(kb+row)*ET + c4];
        }
        __syncthreads();
        for (int k = 0; k < 64; ++k){
            float zt = Zst[k*ET + tf];
            float zf = Zsf[k*ET + tf];
            const float* at = &Ast[k*68 + tr*8];
            const float* af = &Asf[k*68 + tr*8];
            float4 a0 = *(const float4*)(at);
            float4 a1 = *(const float4*)(at+4);
            float4 b0 = *(const float4*)(af);
            float4 b1 = *(const float4*)(af+4);
            accT[0]+=a0.x*zt; accT[1]+=a0.y*zt; accT[2]+=a0.z*zt; accT[3]+=a0.w*zt;
            accT[4]+=a1.x*zt; accT[5]+=a1.y*zt; accT[6]+=a1.z*zt; accT[7]+=a1.w*zt;
            accF[0]+=b0.x*zf; accF[1]+=b0.y*zf; accF[2]+=b0.z*zf; accF[3]+=b0.w*zf;
            accF[4]+=b1.x*zf; accF[5]+=b1.y*zf; accF[6]+=b1.z*zf; accF[7]+=b1.w*zf;
        }
        __syncthreads();
    }
    #pragma unroll
    for (int u = 0; u < 8; ++u){
        size_t ii = (size_t)(i0 + tr*8 + u);
        Pt[(size_t)kc*(N*ET) + ii*ET + tf] = accT[u];
        Pf[(size_t)kc*(N*ET) + ii*ET + tf] = accF[u];
    }
}

// ---- reduce partials + self term + dis*(.)+bias + lrelu + onehot -> feats ----
__global__ __launch_bounds__(256) void k_feats_epi(const float* __restrict__ Pt,
                                                   const float* __restrict__ Pf,
                                                   const float* __restrict__ Zt,
                                                   const float* __restrict__ Zf,
                                                   const float* __restrict__ degT,
                                                   const float* __restrict__ degF,
                                                   const float* __restrict__ bt,
                                                   const float* __restrict__ bfv,
                                                   const float* __restrict__ cols,
                                                   const int* __restrict__ qsize,
                                                   float* __restrict__ feats){
    int idx = blockIdx.x*256 + threadIdx.x;   // over 2048*64
    int i = idx >> 6;
    int f = idx & 63;
    float s, rd, b;
    if (f < ET){
        s = Zt[(size_t)i*ET + f];             // self-loop term (Ah[ii]=1)
        #pragma unroll
        for (int kc = 0; kc < KC_ET; ++kc) s += Pt[(size_t)kc*(N*ET) + (size_t)i*ET + f];
        rd = rsqrtf(1.f + degT[i]);
        b = bt[f];
    } else {
        int g = f - ET;
        s = Zf[(size_t)i*ET + g];
        #pragma unroll
        for (int kc = 0; kc < KC_ET; ++kc) s += Pf[(size_t)kc*(N*ET) + (size_t)i*ET + g];
        rd = rsqrtf(1.f + degF[i]);
        b = bfv[g];
    }
    float v = rd*s + b;
    feats[(size_t)i*FS + f] = v > 0.f ? v : 0.01f*v;
    if (f < NC){
        int nsup = N - qsize[0];
        feats[(size_t)i*FS + 2*ET + f] = (i < nsup) ? cols[f] : 0.f;
    }
}

// ---- Aw[i][j] = (i==j) ? 1 : 1/(L1(fd_i,fd_j)+1e-5) ----
__global__ __launch_bounds__(256) void k_build_aw(const float* __restrict__ feats,
                                                  float* __restrict__ Aw){
    __shared__ float fi[64*65];
    __shared__ float fj[64*65];
    int t = threadIdx.x;
    int i0 = blockIdx.x*64, j0 = blockIdx.y*64;
    {
        int row = t >> 2;
        int seg = (t & 3) * 16;
        const float4* si = (const float4*)(feats + (size_t)(i0+row)*FS + seg);
        const float4* sj = (const float4*)(feats + (size_t)(j0+row)*FS + seg);
        #pragma unroll
        for (int s = 0; s < 4; ++s){
            float4 v = si[s];
            float4 w = sj[s];
            int c = seg + s*4;
            fi[row*65+c+0]=v.x; fi[row*65+c+1]=v.y; fi[row*65+c+2]=v.z; fi[row*65+c+3]=v.w;
            fj[row*65+c+0]=w.x; fj[row*65+c+1]=w.y; fj[row*65+c+2]=w.z; fj[row*65+c+3]=w.w;
        }
    }
    __syncthreads();
    int tx = t & 15, ty = t >> 4;
    float acc[4][4];
    #pragma unroll
    for (int u=0;u<4;++u)
        #pragma unroll
        for (int v=0;v<4;++v) acc[u][v]=0.f;
    for (int k = 0; k < 64; ++k){
        float a0 = fi[(ty*4+0)*65+k], a1 = fi[(ty*4+1)*65+k];
        float a2 = fi[(ty*4+2)*65+k], a3 = fi[(ty*4+3)*65+k];
        float b0 = fj[(tx*4+0)*65+k], b1 = fj[(tx*4+1)*65+k];
        float b2 = fj[(tx*4+2)*65+k], b3 = fj[(tx*4+3)*65+k];
        acc[0][0]+=fabsf(a0-b0); acc[0][1]+=fabsf(a0-b1); acc[0][2]+=fabsf(a0-b2); acc[0][3]+=fabsf(a0-b3);
        acc[1][0]+=fabsf(a1-b0); acc[1][1]+=fabsf(a1-b1); acc[1][2]+=fabsf(a1-b2); acc[1][3]+=fabsf(a1-b3);
        acc[2][0]+=fabsf(a2-b0); acc[2][1]+=fabsf(a2-b1); acc[2][2]+=fabsf(a2-b2); acc[2][3]+=fabsf(a2-b3);
        acc[3][0]+=fabsf(a3-b0); acc[3][1]+=fabsf(a3-b1); acc[3][2]+=fabsf(a3-b2); acc[3][3]+=fabsf(a3-b3);
    }
    #pragma unroll
    for (int u = 0; u < 4; ++u){
        int gi = i0 + ty*4 + u;
        float4 o;
        float* po = (float*)&o;
        #pragma unroll
        for (int v = 0; v < 4; ++v){
            int gj = j0 + tx*4 + v;
            po[v] = (gi==gj) ? 1.0f : 1.0f/(acc[u][v] + 1e-5f);
        }
        *(float4*)(Aw + (size_t)gi*N + j0 + tx*4) = o;
    }
}

// ---- dis_w[row] = rsqrt(rowsum(Aw)) (diag already 1) ----
__global__ __launch_bounds__(256) void k_row_rsqrt(const float* __restrict__ A,
                                                   float* __restrict__ dis){
    int row = blockIdx.x;
    const float4* Ar = (const float4*)(A + (size_t)row*N);
    float s = 0.f;
    for (int i = threadIdx.x; i < N/4; i += 256){
        float4 v = Ar[i];
        s += (v.x+v.y)+(v.z+v.w);
    }
    #pragma unroll
    for (int off = 32; off > 0; off >>= 1) s += __shfl_xor(s, off, 64);
    __shared__ float red[4];
    int wid = threadIdx.x >> 6;
    if ((threadIdx.x & 63) == 0) red[wid] = s;
    __syncthreads();
    if (threadIdx.x == 0){
        float deg = red[0]+red[1]+red[2]+red[3];
        dis[row] = (deg > 0.f) ? 1.0f/sqrtf(deg) : 0.f;
    }
}

// ---- Zc[i][f] = dis_w[i] * (feats[i,0:69] @ Wc[:,f]) ----
__global__ __launch_bounds__(256) void k_featswc(const float* __restrict__ feats,
                                                 const float* __restrict__ Wc,
                                                 const float* __restrict__ disw,
                                                 float* __restrict__ Zc){
    __shared__ float Wcs[FD*EC];   // 34.5 KB
    __shared__ float fr[8][FD+3];
    int t = threadIdx.x; // 256
    for (int idx = t; idx < FD*EC; idx += 256) Wcs[idx] = Wc[idx];
    int i0 = blockIdx.x*8;
    for (int idx = t; idx < 8*FD; idx += 256){
        int r = idx / FD;
        int c = idx - r*FD;
        fr[r][c] = feats[(size_t)(i0+r)*FS + c];
    }
    __syncthreads();
    int f  = t & 127;
    int rh = t >> 7;   // 0..1
    for (int rr = 0; rr < 4; ++rr){
        int r = rh*4 + rr;
        float acc = 0.f;
        #pragma unroll
        for (int d = 0; d < FD; ++d) acc += fr[r][d]*Wcs[d*EC+f];
        int i = i0 + r;
        Zc[(size_t)i*EC + f] = disw[i]*acc;
    }
}

// ---- split-K GEMM: Pe[kc][i][f] = sum_{k in chunk} Aw[i,k]*Zc[k][f] ----
__global__ __launch_bounds__(256) void k_agg_ec(const float* __restrict__ Aw,
                                                const float* __restrict__ Zc,
                                                float* __restrict__ Pe){
    __shared__ float Aws[32*65];
    __shared__ float Zcs[64*EC];
    int t = threadIdx.x;
    int i0 = blockIdx.x*32;
    int kc = blockIdx.y;          // 0..7
    int k0 = kc*256;
    int tf = t & 31, tr = t >> 5; // tr 0..7 -> rows tr*4+v
    int f0 = tf*4;
    float acc[4][4];
    #pragma unroll
    for (int v=0;v<4;++v)
        #pragma unroll
        for (int u=0;u<4;++u) acc[v][u]=0.f;

    for (int kt = 0; kt < 4; ++kt){
        int kb = k0 + kt*64;
        #pragma unroll
        for (int h = 0; h < 2; ++h){
            int id = t + h*256;       // 0..511 float4 ids over 32x64
            int row = id >> 4;
            int c4  = (id & 15)*4;
            float4 v = *(const float4*)&Aw[(size_t)(i0+row)*N + kb + c4];
            Aws[row*65 + c4 + 0] = v.x;
            Aws[row*65 + c4 + 1] = v.y;
            Aws[row*65 + c4 + 2] = v.z;
            Aws[row*65 + c4 + 3] = v.w;
        }
        #pragma unroll
        for (int h = 0; h < 8; ++h){
            int id = t + h*256;       // 0..2047 float4 ids over 64x128
            int row = id >> 5;
            int c4  = (id & 31)*4;
            *(float4*)&Zcs[row*EC + c4] = *(const float4*)&Zc[(size_t)(kb+row)*EC + c4];
        }
        __syncthreads();
        for (int k = 0; k < 64; ++k){
            float4 z = *(const float4*)&Zcs[k*EC + f0];
            float a0 = Aws[(tr*4+0)*65 + k];
            float a1 = Aws[(tr*4+1)*65 + k];
            float a2 = Aws[(tr*4+2)*65 + k];
            float a3 = Aws[(tr*4+3)*65 + k];
            acc[0][0]+=a0*z.x; acc[0][1]+=a0*z.y; acc[0][2]+=a0*z.z; acc[0][3]+=a0*z.w;
            acc[1][0]+=a1*z.x; acc[1][1]+=a1*z.y; acc[1][2]+=a1*z.z; acc[1][3]+=a1*z.w;
            acc[2][0]+=a2*z.x; acc[2][1]+=a2*z.y; acc[2][2]+=a2*z.z; acc[2][3]+=a2*z.w;
            acc[3][0]+=a3*z.x; acc[3][1]+=a3*z.y; acc[3][2]+=a3*z.z; acc[3][3]+=a3*z.w;
        }
        __syncthreads();
    }
    #pragma unroll
    for (int v = 0; v < 4; ++v){
        size_t ii = (size_t)(i0 + tr*4 + v);
        float4 o; o.x=acc[v][0]; o.y=acc[v][1]; o.z=acc[v][2]; o.w=acc[v][3];
        *(float4*)&Pe[(size_t)kc*(N*EC) + ii*EC + f0] = o;
    }
}

// ---- reduce Pe + dis_w*(.)+bc + lrelu -> emb ----
__global__ __launch_bounds__(256) void k_emb_epi(const float* __restrict__ Pe,
                                                 const float* __restrict__ disw,
                                                 const float* __restrict__ bc,
                                                 float* __restrict__ emb){
    int idx = blockIdx.x*256 + threadIdx.x;   // over 2048*128
    int i = idx >> 7, f = idx & 127;
    float s = 0.f;
    #pragma unroll
    for (int kc = 0; kc < KC_EC; ++kc) s += Pe[(size_t)kc*(N*EC) + (size_t)idx];
    float v = disw[i]*s + bc[f];
    emb[idx] = v > 0.f ? v : 0.01f*v;
}

// ---- out[i][c] = emb[i,:] @ Wo[:,c] + bo[c] ----
__global__ __launch_bounds__(256) void k_final(const float* __restrict__ emb,
                                               const float* __restrict__ Wo,
                                               const float* __restrict__ bo,
                                               float* __restrict__ out){
    __shared__ float Wos[EC*NC];
    __shared__ float bos[NC];
    int t = threadIdx.x;
    for (int idx = t; idx < EC*NC; idx += 256) Wos[idx] = Wo[idx];
    if (t < NC) bos[t] = bo[t];
    __syncthreads();
    int idx = blockIdx.x*256 + t;   // grid exact: N*NC/256 = 40
    int i = idx / NC;
    int c = idx - i*NC;
    float acc = bos[c];
    const float* er = emb + (size_t)i*EC;
    #pragma unroll 8
    for (int f = 0; f < EC; ++f) acc += er[f]*Wos[f*NC+c];
    out[idx] = acc;
}

extern "C" void kernel_launch(void* const* d_in, const int* in_sizes, int n_in,
                              void* d_out, int out_size, void* d_ws, size_t ws_size,
                              hipStream_t stream) {
    const float* time_features = (const float*)d_in[0];
    const float* tw            = (const float*)d_in[2];
    const float* freq_features = (const float*)d_in[3];
    const float* fw            = (const float*)d_in[4];
    const int*   labels        = (const int*)d_in[5];
    const int*   qsize         = (const int*)d_in[7];
    const float* Wt  = (const float*)d_in[8];
    const float* bt  = (const float*)d_in[9];
    const float* Wf  = (const float*)d_in[10];
    const float* bfv = (const float*)d_in[11];
    const float* Wc  = (const float*)d_in[12];
    const float* bc  = (const float*)d_in[13];
    const float* Wo  = (const float*)d_in[14];
    const float* bo  = (const float*)d_in[15];
    float* out = (float*)d_out;

    float* ws    = (float*)d_ws;
    float* Zt    = ws;                         // N*ET
    float* Zf    = Zt + (size_t)N*ET;          // N*ET
    float* Zc    = Zf + (size_t)N*ET;          // N*EC
    float* degT  = Zc + (size_t)N*EC;          // N
    float* degF  = degT + N;                   // N
    float* disw  = degF + N;                   // N
    float* colsb = disw + N;                   // 8
    float* feats = colsb + 8;                  // N*FS
    float* emb   = feats + (size_t)N*FS;       // N*EC
    float* Aw    = emb + (size_t)N*EC;         // N*N
    float* Pt    = Aw + (size_t)N*N;           // KC_ET*N*ET
    float* Pf    = Pt + (size_t)KC_ET*N*ET;    // KC_ET*N*ET
    float* Pe    = Pf + (size_t)KC_ET*N*ET;    // KC_EC*N*EC

    hipMemsetAsync(degT, 0, 2*N*sizeof(float), stream);
    k_deg<<<N/16, 256, 0, stream>>>(tw, fw, degT, degF);
    k_labelmask<<<1, 256, 0, stream>>>(labels, colsb);
    k_xw_scale<<<N/8, 256, 0, stream>>>(time_features, Wt, degT, Zt);
    k_xw_scale<<<N/8, 256, 0, stream>>>(freq_features, Wf, degF, Zf);
    k_agg_et<<<dim3(N/64, KC_ET), 256, 0, stream>>>(tw, fw, Zt, Zf, Pt, Pf);
    k_feats_epi<<<(N*64)/256, 256, 0, stream>>>(Pt, Pf, Zt, Zf, degT, degF,
                                                bt, bfv, colsb, qsize, feats);
    k_build_aw<<<dim3(N/64, N/64), 256, 0, stream>>>(feats, Aw);
    k_row_rsqrt<<<N, 256, 0, stream>>>(Aw, disw);
    k_featswc<<<N/8, 256, 0, stream>>>(feats, Wc, disw, Zc);
    k_agg_ec<<<dim3(N/32, KC_EC), 256, 0, stream>>>(Aw, Zc, Pe);
    k_emb_epi<<<(N*EC)/256, 256, 0, stream>>>(Pe, disw, bc, emb);
    k_final<<<(N*NC)/256, 256, 0, stream>>>(emb, Wo, bo, out);
}

// Round 5
// 230.466 us; speedup vs baseline: 2.4795x; 1.3271x over previous
//
#include <hip/hip_runtime.h>
#include <hip/hip_bf16.h>

#define N 2048
#define NM1 2047
#define DT 256
#define ET 32
#define EC 128
#define NC 5
#define FS 80    // feats row stride (floats)
#define FD 69    // used feature cols
#define KC_ET 16 // k-chunks for ET GEMMs (chunk = 128)
#define KC_EC 8  // k-chunks for EC GEMM (chunk = 256)

typedef __hip_bfloat16 bf16;

// ---- deg via shifted column sums ----
// tw[s][p] = A[d,s] with d = p + (p>=s).  For column p: rows s>p -> deg[p],
// rows s<=p -> deg[p+1].  Coalesced column-sum, 4 atomics/thread.
__global__ __launch_bounds__(256) void k_deg(const float* __restrict__ tw,
                                             const float* __restrict__ fw,
                                             float* __restrict__ degT,
                                             float* __restrict__ degF){
    int p = blockIdx.x*256 + threadIdx.x;   // column 0..2047 (2047 invalid)
    if (p >= NM1) return;
    int s0 = blockIdx.y*32;
    float lowT=0.f, highT=0.f, lowF=0.f, highF=0.f;
    #pragma unroll 8
    for (int r = 0; r < 32; ++r){
        int s = s0 + r;
        float vt = tw[(size_t)s*NM1 + p];
        float vf = fw[(size_t)s*NM1 + p];
        if (s <= p){ highT += vt; highF += vf; }
        else       { lowT  += vt; lowF  += vf; }
    }
    atomicAdd(&degT[p],   lowT);
    atomicAdd(&degF[p],   lowF);
    atomicAdd(&degT[p+1], highT);
    atomicAdd(&degF[p+1], highF);
}

// ---- cols[c] = 1 if class c appears in labels ----
__global__ void k_labelmask(const int* __restrict__ labels, float* __restrict__ cols){
    __shared__ float lc[NC];
    int t = threadIdx.x;
    if (t < NC) lc[t] = 0.f;
    __syncthreads();
    for (int i = t; i < N; i += 256){
        int l = labels[i];
        if (l >= 0 && l < NC) lc[l] = 1.f;  // benign race, all write 1.0
    }
    __syncthreads();
    if (t < NC) cols[t] = lc[t];
}

// ---- Z[j][f] = rsqrt(1+deg[j]) * (X[j,:] @ W[:,f]) ----
__global__ __launch_bounds__(256) void k_xw_scale(const float* __restrict__ X,
                                                  const float* __restrict__ W,
                                                  const float* __restrict__ deg,
                                                  float* __restrict__ Z){
    __shared__ float Ws[DT*ET]; // 32 KB
    __shared__ float Xs[8*DT];  // 8 KB
    int t = threadIdx.x;
    for (int idx = t; idx < DT*ET; idx += 256) Ws[idx] = W[idx];
    int i0 = blockIdx.x*8;
    for (int idx = t; idx < 8*DT; idx += 256) Xs[idx] = X[(size_t)i0*DT + idx];
    __syncthreads();
    int r = t >> 5, f = t & 31;
    const float* xr = Xs + r*DT;
    float acc = 0.f;
    #pragma unroll 8
    for (int d = 0; d < DT; ++d) acc += xr[d]*Ws[d*ET+f];
    int i = i0 + r;
    Z[(size_t)i*ET+f] = rsqrtf(1.f + deg[i])*acc;
}

// ---- split-K GEMM: P[kc][i][f] = sum_{k in chunk, k!=i} A[i,k]*Z[k][f], both graphs ----
// A[i,k] = tw[k*2047 + i - (i>k)] (coalesced over i for fixed k)
__global__ __launch_bounds__(256) void k_agg_et(const float* __restrict__ tw,
                                                const float* __restrict__ fw,
                                                const float* __restrict__ Zt,
                                                const float* __restrict__ Zf,
                                                float* __restrict__ Pt,
                                                float* __restrict__ Pf){
    __shared__ float Ast[64*68];
    __shared__ float Asf[64*68];
    __shared__ float Zst[64*ET];
    __shared__ float Zsf[64*ET];
    int t = threadIdx.x;
    int i0 = blockIdx.x*64;
    int kc = blockIdx.y;          // 0..15
    int k0 = kc*128;
    int lane_i = t & 63;
    int krow0  = (t >> 6)*16;     // 16 k-rows per thread
    int gi = i0 + lane_i;
    int tf = t & 31;
    int tr = t >> 5;              // 0..7  -> rows tr*8+u
    float accT[8], accF[8];
    #pragma unroll
    for (int u = 0; u < 8; ++u){ accT[u]=0.f; accF[u]=0.f; }

    for (int kt = 0; kt < 2; ++kt){
        int kb = k0 + kt*64;
        #pragma unroll 4
        for (int e = 0; e < 16; ++e){
            int kl = krow0 + e;
            int k  = kb + kl;
            float vt, vf;
            if (gi == k){ vt = 0.f; vf = 0.f; }
            else {
                size_t base = (size_t)k*NM1 + gi - (gi > k ? 1 : 0);
                vt = tw[base]; vf = fw[base];
            }
            Ast[kl*68 + lane_i] = vt;
            Asf[kl*68 + lane_i] = vf;
        }
        #pragma unroll
        for (int h = 0; h < 2; ++h){
            int id = t + h*256;       // 0..511 float4 ids
            int row = id >> 3;
            int c4  = (id & 7)*4;
            *(float4*)&Zst[row*ET + c4] = *(const float4*)&Zt[(size_t)(kb+row)*ET + c4];
            *(float4*)&Zsf[row*ET + c4] = *(const float4*)&Zf[(size_t)(kb+row)*ET + c4];
        }
        __syncthreads();
        for (int k = 0; k < 64; ++k){
            float zt = Zst[k*ET + tf];
            float zf = Zsf[k*ET + tf];
            const float* at = &Ast[k*68 + tr*8];
            const float* af = &Asf[k*68 + tr*8];
            float4 a0 = *(const float4*)(at);
            float4 a1 = *(const float4*)(at+4);
            float4 b0 = *(const float4*)(af);
            float4 b1 = *(const float4*)(af+4);
            accT[0]+=a0.x*zt; accT[1]+=a0.y*zt; accT[2]+=a0.z*zt; accT[3]+=a0.w*zt;
            accT[4]+=a1.x*zt; accT[5]+=a1.y*zt; accT[6]+=a1.z*zt; accT[7]+=a1.w*zt;
            accF[0]+=b0.x*zf; accF[1]+=b0.y*zf; accF[2]+=b0.z*zf; accF[3]+=b0.w*zf;
            accF[4]+=b1.x*zf; accF[5]+=b1.y*zf; accF[6]+=b1.z*zf; accF[7]+=b1.w*zf;
        }
        __syncthreads();
    }
    #pragma unroll
    for (int u = 0; u < 8; ++u){
        size_t ii = (size_t)(i0 + tr*8 + u);
        Pt[(size_t)kc*(N*ET) + ii*ET + tf] = accT[u];
        Pf[(size_t)kc*(N*ET) + ii*ET + tf] = accF[u];
    }
}

// ---- reduce partials + self term + dis*(.)+bias + lrelu + onehot -> feats ----
__global__ __launch_bounds__(256) void k_feats_epi(const float* __restrict__ Pt,
                                                   const float* __restrict__ Pf,
                                                   const float* __restrict__ Zt,
                                                   const float* __restrict__ Zf,
                                                   const float* __restrict__ degT,
                                                   const float* __restrict__ degF,
                                                   const float* __restrict__ bt,
                                                   const float* __restrict__ bfv,
                                                   const float* __restrict__ cols,
                                                   const int* __restrict__ qsize,
                                                   float* __restrict__ feats){
    int idx = blockIdx.x*256 + threadIdx.x;   // over 2048*64
    int i = idx >> 6;
    int f = idx & 63;
    float s, rd, b;
    if (f < ET){
        s = Zt[(size_t)i*ET + f];             // self-loop term (Ah[ii]=1)
        #pragma unroll
        for (int kc = 0; kc < KC_ET; ++kc) s += Pt[(size_t)kc*(N*ET) + (size_t)i*ET + f];
        rd = rsqrtf(1.f + degT[i]);
        b = bt[f];
    } else {
        int g = f - ET;
        s = Zf[(size_t)i*ET + g];
        #pragma unroll
        for (int kc = 0; kc < KC_ET; ++kc) s += Pf[(size_t)kc*(N*ET) + (size_t)i*ET + g];
        rd = rsqrtf(1.f + degF[i]);
        b = bfv[g];
    }
    float v = rd*s + b;
    feats[(size_t)i*FS + f] = v > 0.f ? v : 0.01f*v;
    if (f < NC){
        int nsup = N - qsize[0];
        feats[(size_t)i*FS + 2*ET + f] = (i < nsup) ? cols[f] : 0.f;
    }
}

// ---- Aw[i][j] = (i==j) ? 1 : 1/(L1(fd_i,fd_j)+1e-5) ----
__global__ __launch_bounds__(256) void k_build_aw(const float* __restrict__ feats,
                                                  float* __restrict__ Aw){
    __shared__ float fi[64*65];
    __shared__ float fj[64*65];
    int t = threadIdx.x;
    int i0 = blockIdx.x*64, j0 = blockIdx.y*64;
    {
        int row = t >> 2;
        int seg = (t & 3) * 16;
        const float4* si = (const float4*)(feats + (size_t)(i0+row)*FS + seg);
        const float4* sj = (const float4*)(feats + (size_t)(j0+row)*FS + seg);
        #pragma unroll
        for (int s = 0; s < 4; ++s){
            float4 v = si[s];
            float4 w = sj[s];
            int c = seg + s*4;
            fi[row*65+c+0]=v.x; fi[row*65+c+1]=v.y; fi[row*65+c+2]=v.z; fi[row*65+c+3]=v.w;
            fj[row*65+c+0]=w.x; fj[row*65+c+1]=w.y; fj[row*65+c+2]=w.z; fj[row*65+c+3]=w.w;
        }
    }
    __syncthreads();
    int tx = t & 15, ty = t >> 4;
    float acc[4][4];
    #pragma unroll
    for (int u=0;u<4;++u)
        #pragma unroll
        for (int v=0;v<4;++v) acc[u][v]=0.f;
    for (int k = 0; k < 64; ++k){
        float a0 = fi[(ty*4+0)*65+k], a1 = fi[(ty*4+1)*65+k];
        float a2 = fi[(ty*4+2)*65+k], a3 = fi[(ty*4+3)*65+k];
        float b0 = fj[(tx*4+0)*65+k], b1 = fj[(tx*4+1)*65+k];
        float b2 = fj[(tx*4+2)*65+k], b3 = fj[(tx*4+3)*65+k];
        acc[0][0]+=fabsf(a0-b0); acc[0][1]+=fabsf(a0-b1); acc[0][2]+=fabsf(a0-b2); acc[0][3]+=fabsf(a0-b3);
        acc[1][0]+=fabsf(a1-b0); acc[1][1]+=fabsf(a1-b1); acc[1][2]+=fabsf(a1-b2); acc[1][3]+=fabsf(a1-b3);
        acc[2][0]+=fabsf(a2-b0); acc[2][1]+=fabsf(a2-b1); acc[2][2]+=fabsf(a2-b2); acc[2][3]+=fabsf(a2-b3);
        acc[3][0]+=fabsf(a3-b0); acc[3][1]+=fabsf(a3-b1); acc[3][2]+=fabsf(a3-b2); acc[3][3]+=fabsf(a3-b3);
    }
    #pragma unroll
    for (int u = 0; u < 4; ++u){
        int gi = i0 + ty*4 + u;
        float4 o;
        float* po = (float*)&o;
        #pragma unroll
        for (int v = 0; v < 4; ++v){
            int gj = j0 + tx*4 + v;
            po[v] = (gi==gj) ? 1.0f : 1.0f/(acc[u][v] + 1e-5f);
        }
        *(float4*)(Aw + (size_t)gi*N + j0 + tx*4) = o;
    }
}

// ---- dis_w[row] = rsqrt(rowsum(Aw)) (diag already 1) ----
__global__ __launch_bounds__(256) void k_row_rsqrt(const float* __restrict__ A,
                                                   float* __restrict__ dis){
    int row = blockIdx.x;
    const float4* Ar = (const float4*)(A + (size_t)row*N);
    float s = 0.f;
    for (int i = threadIdx.x; i < N/4; i += 256){
        float4 v = Ar[i];
        s += (v.x+v.y)+(v.z+v.w);
    }
    #pragma unroll
    for (int off = 32; off > 0; off >>= 1) s += __shfl_xor(s, off, 64);
    __shared__ float red[4];
    int wid = threadIdx.x >> 6;
    if ((threadIdx.x & 63) == 0) red[wid] = s;
    __syncthreads();
    if (threadIdx.x == 0){
        float deg = red[0]+red[1]+red[2]+red[3];
        dis[row] = (deg > 0.f) ? 1.0f/sqrtf(deg) : 0.f;
    }
}

// ---- Zc[i][f] = dis_w[i] * (feats[i,0:69] @ Wc[:,f]) ----
__global__ __launch_bounds__(256) void k_featswc(const float* __restrict__ feats,
                                                 const float* __restrict__ Wc,
                                                 const float* __restrict__ disw,
                                                 float* __restrict__ Zc){
    __shared__ float Wcs[FD*EC];   // 34.5 KB
    __shared__ float fr[8][FD+3];
    int t = threadIdx.x; // 256
    for (int idx = t; idx < FD*EC; idx += 256) Wcs[idx] = Wc[idx];
    int i0 = blockIdx.x*8;
    for (int idx = t; idx < 8*FD; idx += 256){
        int r = idx / FD;
        int c = idx - r*FD;
        fr[r][c] = feats[(size_t)(i0+r)*FS + c];
    }
    __syncthreads();
    int f  = t & 127;
    int rh = t >> 7;   // 0..1
    for (int rr = 0; rr < 4; ++rr){
        int r = rh*4 + rr;
        float acc = 0.f;
        #pragma unroll
        for (int d = 0; d < FD; ++d) acc += fr[r][d]*Wcs[d*EC+f];
        int i = i0 + r;
        Zc[(size_t)i*EC + f] = disw[i]*acc;
    }
}

// ---- split-K GEMM: Pe[kc][i][f] = sum_{k in chunk} Aw[i,k]*Zc[k][f] ----
__global__ __launch_bounds__(256) void k_agg_ec(const float* __restrict__ Aw,
                                                const float* __restrict__ Zc,
                                                float* __restrict__ Pe){
    __shared__ float Aws[32*65];
    __shared__ float Zcs[64*EC];
    int t = threadIdx.x;
    int i0 = blockIdx.x*32;
    int kc = blockIdx.y;          // 0..7
    int k0 = kc*256;
    int tf = t & 31, tr = t >> 5; // tr 0..7 -> rows tr*4+v
    int f0 = tf*4;
    float acc[4][4];
    #pragma unroll
    for (int v=0;v<4;++v)
        #pragma unroll
        for (int u=0;u<4;++u) acc[v][u]=0.f;

    for (int kt = 0; kt < 4; ++kt){
        int kb = k0 + kt*64;
        #pragma unroll
        for (int h = 0; h < 2; ++h){
            int id = t + h*256;       // 0..511 float4 ids over 32x64
            int row = id >> 4;
            int c4  = (id & 15)*4;
            float4 v = *(const float4*)&Aw[(size_t)(i0+row)*N + kb + c4];
            Aws[row*65 + c4 + 0] = v.x;
            Aws[row*65 + c4 + 1] = v.y;
            Aws[row*65 + c4 + 2] = v.z;
            Aws[row*65 + c4 + 3] = v.w;
        }
        #pragma unroll
        for (int h = 0; h < 8; ++h){
            int id = t + h*256;       // 0..2047 float4 ids over 64x128
            int row = id >> 5;
            int c4  = (id & 31)*4;
            *(float4*)&Zcs[row*EC + c4] = *(const float4*)&Zc[(size_t)(kb+row)*EC + c4];
        }
        __syncthreads();
        for (int k = 0; k < 64; ++k){
            float4 z = *(const float4*)&Zcs[k*EC + f0];
            float a0 = Aws[(tr*4+0)*65 + k];
            float a1 = Aws[(tr*4+1)*65 + k];
            float a2 = Aws[(tr*4+2)*65 + k];
            float a3 = Aws[(tr*4+3)*65 + k];
            acc[0][0]+=a0*z.x; acc[0][1]+=a0*z.y; acc[0][2]+=a0*z.z; acc[0][3]+=a0*z.w;
            acc[1][0]+=a1*z.x; acc[1][1]+=a1*z.y; acc[1][2]+=a1*z.z; acc[1][3]+=a1*z.w;
            acc[2][0]+=a2*z.x; acc[2][1]+=a2*z.y; acc[2][2]+=a2*z.z; acc[2][3]+=a2*z.w;
            acc[3][0]+=a3*z.x; acc[3][1]+=a3*z.y; acc[3][2]+=a3*z.z; acc[3][3]+=a3*z.w;
        }
        __syncthreads();
    }
    #pragma unroll
    for (int v = 0; v < 4; ++v){
        size_t ii = (size_t)(i0 + tr*4 + v);
        float4 o; o.x=acc[v][0]; o.y=acc[v][1]; o.z=acc[v][2]; o.w=acc[v][3];
        *(float4*)&Pe[(size_t)kc*(N*EC) + ii*EC + f0] = o;
    }
}

// ---- reduce Pe + dis_w*(.)+bc + lrelu -> emb ----
__global__ __launch_bounds__(256) void k_emb_epi(const float* __restrict__ Pe,
                                                 const float* __restrict__ disw,
                                                 const float* __restrict__ bc,
                                                 float* __restrict__ emb){
    int idx = blockIdx.x*256 + threadIdx.x;   // over 2048*128
    int i = idx >> 7, f = idx & 127;
    float s = 0.f;
    #pragma unroll
    for (int kc = 0; kc < KC_EC; ++kc) s += Pe[(size_t)kc*(N*EC) + (size_t)idx];
    float v = disw[i]*s + bc[f];
    emb[idx] = v > 0.f ? v : 0.01f*v;
}

// ---- out[i][c] = emb[i,:] @ Wo[:,c] + bo[c] ----
__global__ __launch_bounds__(256) void k_final(const float* __restrict__ emb,
                                               const float* __restrict__ Wo,
                                               const float* __restrict__ bo,
                                               float* __restrict__ out){
    __shared__ float Wos[EC*NC];
    __shared__ float bos[NC];
    int t = threadIdx.x;
    for (int idx = t; idx < EC*NC; idx += 256) Wos[idx] = Wo[idx];
    if (t < NC) bos[t] = bo[t];
    __syncthreads();
    int idx = blockIdx.x*256 + t;   // grid exact: N*NC/256 = 40
    int i = idx / NC;
    int c = idx - i*NC;
    float acc = bos[c];
    const float* er = emb + (size_t)i*EC;
    #pragma unroll 8
    for (int f = 0; f < EC; ++f) acc += er[f]*Wos[f*NC+c];
    out[idx] = acc;
}

extern "C" void kernel_launch(void* const* d_in, const int* in_sizes, int n_in,
                              void* d_out, int out_size, void* d_ws, size_t ws_size,
                              hipStream_t stream) {
    const float* time_features = (const float*)d_in[0];
    const float* tw            = (const float*)d_in[2];
    const float* freq_features = (const float*)d_in[3];
    const float* fw            = (const float*)d_in[4];
    const int*   labels        = (const int*)d_in[5];
    const int*   qsize         = (const int*)d_in[7];
    const float* Wt  = (const float*)d_in[8];
    const float* bt  = (const float*)d_in[9];
    const float* Wf  = (const float*)d_in[10];
    const float* bfv = (const float*)d_in[11];
    const float* Wc  = (const float*)d_in[12];
    const float* bc  = (const float*)d_in[13];
    const float* Wo  = (const float*)d_in[14];
    const float* bo  = (const float*)d_in[15];
    float* out = (float*)d_out;

    float* ws    = (float*)d_ws;
    float* Zt    = ws;                         // N*ET
    float* Zf    = Zt + (size_t)N*ET;          // N*ET
    float* Zc    = Zf + (size_t)N*ET;          // N*EC
    float* degT  = Zc + (size_t)N*EC;          // N
    float* degF  = degT + N;                   // N
    float* disw  = degF + N;                   // N
    float* colsb = disw + N;                   // 8
    float* feats = colsb + 8;                  // N*FS
    float* emb   = feats + (size_t)N*FS;       // N*EC
    float* Aw    = emb + (size_t)N*EC;         // N*N
    float* Pt    = Aw + (size_t)N*N;           // KC_ET*N*ET
    float* Pf    = Pt + (size_t)KC_ET*N*ET;    // KC_ET*N*ET
    float* Pe    = Pf + (size_t)KC_ET*N*ET;    // KC_EC*N*EC

    hipMemsetAsync(degT, 0, 2*N*sizeof(float), stream);
    k_deg<<<dim3(8, 64), 256, 0, stream>>>(tw, fw, degT, degF);
    k_labelmask<<<1, 256, 0, stream>>>(labels, colsb);
    k_xw_scale<<<N/8, 256, 0, stream>>>(time_features, Wt, degT, Zt);
    k_xw_scale<<<N/8, 256, 0, stream>>>(freq_features, Wf, degF, Zf);
    k_agg_et<<<dim3(N/64, KC_ET), 256, 0, stream>>>(tw, fw, Zt, Zf, Pt, Pf);
    k_feats_epi<<<(N*64)/256, 256, 0, stream>>>(Pt, Pf, Zt, Zf, degT, degF,
                                                bt, bfv, colsb, qsize, feats);
    k_build_aw<<<dim3(N/64, N/64), 256, 0, stream>>>(feats, Aw);
    k_row_rsqrt<<<N, 256, 0, stream>>>(Aw, disw);
    k_featswc<<<N/8, 256, 0, stream>>>(feats, Wc, disw, Zc);
    k_agg_ec<<<dim3(N/32, KC_EC), 256, 0, stream>>>(Aw, Zc, Pe);
    k_emb_epi<<<(N*EC)/256, 256, 0, stream>>>(Pe, disw, bc, emb);
    k_final<<<(N*NC)/256, 256, 0, stream>>>(emb, Wo, bo, out);
}